// Round 20
// baseline (135.064 us; speedup 1.0000x reference)
//
#include <hip/hip_runtime.h>
#include <hip/hip_bf16.h>

// Fused attention fwd: x@Wqkv(+RoPE fused) -> causal flash attn (bf16 MFMA) -> @Wout
// B=2 T=2048 D=1024 H=16 DH=64
// Best benched config (R19): 135.0us total; k_attn ~59.5us; + T5 setprio this round.
#define B_ 2
#define T_ 2048
#define D_ 1024
#define H_ 16
#define DH_ 64
#define N3_ 3072
#define M_ 4096

typedef __attribute__((ext_vector_type(8))) short short8;      // 8 bf16 (4 VGPR) MFMA A/B frag
typedef __attribute__((ext_vector_type(4))) float f32x4;       // MFMA C/D frag
typedef __attribute__((ext_vector_type(4))) unsigned short ushort4v;

// native f32->bf16 (compiler emits hw cvt; RNE) [m240: scalar cast is the fast path]
__device__ __forceinline__ unsigned short f2bf(float f) {
  return __builtin_bit_cast(unsigned short, __hip_bfloat16(f));
}
__device__ __forceinline__ float bf2f(unsigned short u) {
  union { unsigned u; float f; } v; v.u = ((unsigned)u) << 16;
  return v.f;
}

// async global->LDS, 16B per lane; LDS dest is WAVE-UNIFORM base + lane*16 [m97/m104]
__device__ __forceinline__ void gload_lds16(const unsigned short* g, unsigned short* l) {
  __builtin_amdgcn_global_load_lds((const __attribute__((address_space(1))) void*)g,
                                   (__attribute__((address_space(3))) void*)l, 16, 0, 0);
}

// ---------- f32 -> bf16 bulk convert (4 elems/thread, exact grid) ----------
__global__ __launch_bounds__(256)
void k_cvt(const float* __restrict__ in, unsigned short* __restrict__ out) {
  int i = (blockIdx.x * 256 + threadIdx.x) * 4;
  f32x4 v = *(const f32x4*)&in[i];
  ushort4v o;
  o[0] = f2bf(v[0]); o[1] = f2bf(v[1]); o[2] = f2bf(v[2]); o[3] = f2bf(v[3]);
  *(ushort4v*)&out[i] = o;
}

// ---------- transpose f32 [R][C] -> bf16 [C][R] (64x64 LDS tile) ----------
__global__ __launch_bounds__(256)
void k_transpose(const float* __restrict__ in, unsigned short* __restrict__ out,
                 int R, int C) {
  __shared__ float tile[64][65];
  int c0 = blockIdx.x * 64, r0 = blockIdx.y * 64;
  int tx = threadIdx.x & 63, ty = threadIdx.x >> 6;
#pragma unroll
  for (int i = 0; i < 64; i += 4)
    tile[ty + i][tx] = in[(size_t)(r0 + ty + i) * C + c0 + tx];
  __syncthreads();
#pragma unroll
  for (int i = 0; i < 64; i += 4)
    out[(size_t)(c0 + ty + i) * R + r0 + tx] = f2bf(tile[tx][ty + i]);
}

// ---------- GEMM core (2-phase dbuf, BK=32, both-sides swizzle) [R17: -14.5us] ----------
#define GEMM_DBUF_LOOP(A_, Bt_, Kx_)                                               \
  const int l4 = lane >> 2, c4 = lane & 3;                                         \
  const int srcswz = ((c4 ^ (l4 & 3) ^ ((l4 >> 2) & 3)) << 3);                     \
  const int fswz = (((l15 & 3) ^ ((l15 >> 2) & 3)) << 3);                          \
  auto stage = [&](int buf, int k0) {                                              \
    _Pragma("unroll")                                                              \
    for (int i = 0; i < 2; ++i)                                                    \
      gload_lds16(&A_[(size_t)(m0 + wid * 32 + i * 16 + l4) * Kx_ + k0 + srcswz],  \
                  &As[buf * 4096 + (wid * 32 + i * 16) * 32]);                     \
    _Pragma("unroll")                                                              \
    for (int i = 0; i < 2; ++i)                                                    \
      gload_lds16(&Bt_[(size_t)(n0 + wid * 32 + i * 16 + l4) * Kx_ + k0 + srcswz], \
                  &Bs[buf * 4096 + (wid * 32 + i * 16) * 32]);                     \
  };                                                                               \
  const int KI = (Kx_) >> 5;                                                       \
  stage(0, 0);                                                                     \
  for (int it = 0; it < KI; ++it) {                                                \
    __syncthreads();                                                               \
    if (it + 1 < KI) stage((it + 1) & 1, (it + 1) << 5);                           \
    const unsigned short* As_ = &As[(it & 1) * 4096];                              \
    const unsigned short* Bs_ = &Bs[(it & 1) * 4096];                              \
    short8 af[4], bfr[4];                                                          \
    _Pragma("unroll")                                                              \
    for (int mi = 0; mi < 4; ++mi)                                                 \
      af[mi] = *(const short8*)&As_[(wr * 64 + mi * 16 + l15) * 32 +               \
                                    ((lg << 3) ^ fswz)];                           \
    _Pragma("unroll")                                                              \
    for (int ni = 0; ni < 4; ++ni)                                                 \
      bfr[ni] = *(const short8*)&Bs_[(wc * 64 + ni * 16 + l15) * 32 +              \
                                     ((lg << 3) ^ fswz)];                          \
    _Pragma("unroll")                                                              \
    for (int mi = 0; mi < 4; ++mi)                                                 \
      _Pragma("unroll")                                                            \
      for (int ni = 0; ni < 4; ++ni)                                               \
        acc[mi][ni] = __builtin_amdgcn_mfma_f32_16x16x32_bf16(af[mi], bfr[ni],     \
                                                              acc[mi][ni], 0, 0, 0); \
  }

// ---------- GEMM: C[M][N] = A[M][K] @ Bt[N][K]^T, bf16 in, OUT_T out ----------
template <typename OUT_T>
__global__ __launch_bounds__(256)
void k_gemm_bt(const unsigned short* __restrict__ A, const unsigned short* __restrict__ Bt,
               OUT_T* __restrict__ C, int Mx, int Nx, int Kx) {
  __shared__ __align__(16) unsigned short As[2 * 128 * 32];
  __shared__ __align__(16) unsigned short Bs[2 * 128 * 32];
  const int tid = threadIdx.x;
  const int lane = tid & 63;
  const int l15 = lane & 15, lg = lane >> 4;
  const int wid = tid >> 6;
  const int wr = wid >> 1, wc = wid & 1;
  const int m0 = blockIdx.y * 128, n0 = blockIdx.x * 128;

  const f32x4 zero4 = {0.f, 0.f, 0.f, 0.f};
  f32x4 acc[4][4];
#pragma unroll
  for (int mi = 0; mi < 4; ++mi)
#pragma unroll
    for (int ni = 0; ni < 4; ++ni) acc[mi][ni] = zero4;

  GEMM_DBUF_LOOP(A, Bt, Kx)

  // C/D layout: reg j -> row (lg*4+j), col l15  [verified m89/m91]
#pragma unroll
  for (int mi = 0; mi < 4; ++mi)
#pragma unroll
    for (int ni = 0; ni < 4; ++ni)
#pragma unroll
      for (int j = 0; j < 4; ++j) {
        int row = m0 + wr * 64 + mi * 16 + lg * 4 + j;
        int col = n0 + wc * 64 + ni * 16 + l15;
        float v = acc[mi][ni][j];
        if constexpr (sizeof(OUT_T) == 2) C[(size_t)row * Nx + col] = f2bf(v);
        else                              C[(size_t)row * Nx + col] = v;
      }
}

// ---------- fused QKV GEMM + RoPE + layout ----------
// C = Xb[4096][1024] @ Wqkv_t^T -> per-region epilogue:
//   cols [0,1024):   Q rope + 1/8 scale -> Q [BH][T][DH]
//   cols [1024,2048): K rope            -> K [BH][T][DH]
//   cols [2048,3072): V passthrough      -> Vt [BH][DH][T]
// RoPE pair (dh, dh+32) = (acc[mi][ni], acc[mi][ni+2]) for ni in {0,1} — in-register.
__global__ __launch_bounds__(256)
void k_gemm_qkv_rope(const unsigned short* __restrict__ A, const unsigned short* __restrict__ Bt,
                     const float* __restrict__ cosT, const float* __restrict__ sinT,
                     unsigned short* __restrict__ Q, unsigned short* __restrict__ K,
                     unsigned short* __restrict__ Vt) {
  __shared__ __align__(16) unsigned short As[2 * 128 * 32];
  __shared__ __align__(16) unsigned short Bs[2 * 128 * 32];
  const int tid = threadIdx.x;
  const int lane = tid & 63;
  const int l15 = lane & 15, lg = lane >> 4;
  const int wid = tid >> 6;
  const int wr = wid >> 1, wc = wid & 1;
  const int m0 = blockIdx.y * 128, n0 = blockIdx.x * 128;

  const f32x4 zero4 = {0.f, 0.f, 0.f, 0.f};
  f32x4 acc[4][4];
#pragma unroll
  for (int mi = 0; mi < 4; ++mi)
#pragma unroll
    for (int ni = 0; ni < 4; ++ni) acc[mi][ni] = zero4;

  GEMM_DBUF_LOOP(A, Bt, D_)

  const int region = n0 >> 10;                 // 0=Q 1=K 2=V (tile-aligned boundaries)
  const int h = (((n0 & 1023)) + wc * 64) >> 6;   // head of this wave's 64-col block
  if (region < 2) {
    unsigned short* out = (region == 0) ? Q : K;
    const float scale = (region == 0) ? 0.125f : 1.f;   // attn 1/sqrt(64) folded into Q
#pragma unroll
    for (int mi = 0; mi < 4; ++mi)
#pragma unroll
      for (int j = 0; j < 4; ++j) {
        int row = m0 + wr * 64 + mi * 16 + lg * 4 + j;
        int b = row >> 11, t = row & (T_ - 1);
        size_t obase = ((size_t)(b * H_ + h) * T_ + t) * DH_;
#pragma unroll
        for (int ni = 0; ni < 2; ++ni) {
          int dh = ni * 16 + l15;              // 0..31
          float cs = cosT[t * 32 + dh], sn = sinT[t * 32 + dh];
          float x1 = acc[mi][ni][j], x2 = acc[mi][ni + 2][j];
          out[obase + dh]      = f2bf((x1 * cs - x2 * sn) * scale);
          out[obase + dh + 32] = f2bf((x2 * cs + x1 * sn) * scale);
        }
      }
  } else {
#pragma unroll
    for (int mi = 0; mi < 4; ++mi) {
      int row0 = m0 + wr * 64 + mi * 16 + lg * 4;
      int b = row0 >> 11, t0 = row0 & (T_ - 1);
#pragma unroll
      for (int ni = 0; ni < 4; ++ni) {
        int col = (n0 - 2048) + wc * 64 + ni * 16 + l15;   // 0..1023
        int hv = col >> 6, dh = col & 63;
        ushort4v pk;
#pragma unroll
        for (int j = 0; j < 4; ++j) pk[j] = f2bf(acc[mi][ni][j]);
        *(ushort4v*)&Vt[((size_t)(b * H_ + hv) * DH_ + dh) * T_ + t0] = pk;
      }
    }
  }
}

// ---------- causal flash attention (block-cooperative, deferred-softmax pipeline) ----------
// [R17/R19 benched: ~59.5us] 4 waves x 16 q-rows, 1024 blocks. KV 64-key tiles:
// K 2-deep, V 3-deep LDS via gload_lds (both-sides swizzle). T15 att[2] pipeline
// (QK^T(t) || softmax+PV(t-1)). P via LDS stride-72. __expf softmax, defer-max
// THR=8, XCD-chunked swizzle. + T5 s_setprio around MFMA clusters (m191: attn
// +4-7%; role-diverse waves here from T15 split + phase-diverse blocks).
// Falsified: 32-row waves (R7), de-staging (R11), shuffle-P (R12), exp2f (R13),
// P-swizzle (R14), 8-wave (R18).
__global__ __launch_bounds__(256)
void k_attn(const unsigned short* __restrict__ Q, const unsigned short* __restrict__ K,
            const unsigned short* __restrict__ Vt, unsigned short* __restrict__ O) {
  __shared__ __align__(16) unsigned short Ks[2 * 64 * 64];   // [buf][r][chunk^(r&7)] 8KB/buf
  __shared__ __align__(16) unsigned short Vs[3 * 64 * 64];   // 3-deep, rows = dh
  __shared__ __align__(16) unsigned short Pl[4][16][72];     // per-wave P tile (64 + pad 8)
  const int tid = threadIdx.x;
  const int wid = tid >> 6, lane = tid & 63;
  const int l15 = lane & 15, lg = lane >> 4;
  const int l8 = lane >> 3, c8 = lane & 7;
  const int srcoff = (c8 ^ l8) << 3;          // swizzled source chunk (ushort units)
  // XCD-chunked bijective swizzle (nwg=1024): 128 blocks/XCD = 4 heads = 2MB K/V in L2.
  const int wg = (blockIdx.x & 7) * 128 + (blockIdx.x >> 3);
  const int qb = 31 - (wg & 31);              // reversed: longest jobs first
  const int hb = wg >> 5;                     // b*H + h
  const int qblk = qb * 64;
  const int q0 = qblk + wid * 16;
  const size_t hbase = (size_t)hb * T_ * DH_;
  const unsigned short* Qh = Q + hbase;
  const unsigned short* Kh = K + hbase;
  const unsigned short* Vh = Vt + hbase;      // [DH][T]
  unsigned short* Pw = &Pl[wid][0][0];

  // Q^T B-frags, hoisted (b[i] = Q[q0+l15][kk*32+lg*8+i])
  short8 bq0 = *(const short8*)&Qh[(q0 + l15) * DH_ + lg * 8];
  short8 bq1 = *(const short8*)&Qh[(q0 + l15) * DH_ + 32 + lg * 8];

  // hoisted swizzled LDS read offsets (kt-invariant; unrolled-const indexed)
  int koffA[4], koffB[4], voff[2][4];
#pragma unroll
  for (int g = 0; g < 4; ++g) {
    int r = g * 16 + l15;
    koffA[g] = r * 64 + (((lg)     ^ (r & 7)) << 3);
    koffB[g] = r * 64 + (((4 + lg) ^ (r & 7)) << 3);
  }
#pragma unroll
  for (int ks = 0; ks < 2; ++ks)
#pragma unroll
    for (int nb = 0; nb < 4; ++nb) {
      int r = nb * 16 + l15;
      voff[ks][nb] = r * 64 + (((ks * 4 + lg) ^ (r & 7)) << 3);
    }

  const f32x4 zero4 = {0.f, 0.f, 0.f, 0.f};
  f32x4 accO[4];
#pragma unroll
  for (int nb = 0; nb < 4; ++nb) accO[nb] = zero4;
  float m_run = -INFINITY, l_run = 0.f;
  const int qg = q0 + l15;
  const int nt = qb + 1;                      // block's 64-key tile count

  // stage K into Ks[t&1], V into Vs[t%3]: LDS[r][c] = X[r][c^(r&7)]
  auto stage = [&](int t) {
    const int kt = t << 6;
    if (wid < 2) {
      unsigned short* kb = &Ks[(t & 1) * 4096];
      const unsigned short* Kt = Kh + (size_t)kt * DH_;
#pragma unroll
      for (int i = 0; i < 4; ++i)
        gload_lds16(&Kt[(wid * 32 + i * 8 + l8) * DH_ + srcoff],
                    &kb[(wid * 4 + i) * 512]);
    } else {
      unsigned short* vb = &Vs[(t % 3) * 4096];
      const unsigned short* Vg = Vh + kt;
#pragma unroll
      for (int i = 0; i < 4; ++i)
        gload_lds16(&Vg[((wid - 2) * 32 + i * 8 + l8) * T_ + srcoff],
                    &vb[((wid - 2) * 4 + i) * 512]);
    }
  };

  // QK^T for tile t from Ks[t&1] into cg[4]  [T5: prio boost over peers' VALU]
  auto QKT = [&](int t, f32x4* cg) {
    const unsigned short* Kb_ = &Ks[(t & 1) * 4096];
    __builtin_amdgcn_s_setprio(1);
#pragma unroll
    for (int g = 0; g < 4; ++g) {
      short8 a0 = *(const short8*)&Kb_[koffA[g]];
      short8 a1 = *(const short8*)&Kb_[koffB[g]];
      cg[g] = __builtin_amdgcn_mfma_f32_16x16x32_bf16(a0, bq0, zero4, 0, 0, 0);
      cg[g] = __builtin_amdgcn_mfma_f32_16x16x32_bf16(a1, bq1, cg[g], 0, 0, 0);
    }
    __builtin_amdgcn_s_setprio(0);
  };

  // mask + online softmax + P write + PV for tile t (V from Vs[t%3])
  auto SOFTPV = [&](int t, f32x4* cg) {
    const int kt = t << 6;
    const unsigned short* Vb_ = &Vs[(t % 3) * 4096];
    float s[16];
#pragma unroll
    for (int g = 0; g < 4; ++g)
#pragma unroll
      for (int j = 0; j < 4; ++j) s[g * 4 + j] = cg[g][j];
    if (kt + 63 > q0) {                       // boundary tile: causal mask
#pragma unroll
      for (int g = 0; g < 4; ++g) {
        int kb0 = kt + g * 16 + lg * 4;
#pragma unroll
        for (int j = 0; j < 4; ++j)
          if (kb0 + j > qg) s[g * 4 + j] = -INFINITY;
      }
    }
    // tree max (depth 4)
    float t8[8];
#pragma unroll
    for (int j = 0; j < 8; ++j) t8[j] = fmaxf(s[j], s[j + 8]);
    float t4a = fmaxf(t8[0], t8[4]), t4b = fmaxf(t8[1], t8[5]);
    float t4c = fmaxf(t8[2], t8[6]), t4d = fmaxf(t8[3], t8[7]);
    float pm = fmaxf(fmaxf(t4a, t4b), fmaxf(t4c, t4d));
    pm = fmaxf(pm, __shfl_xor(pm, 16));
    pm = fmaxf(pm, __shfl_xor(pm, 32));
    // defer-max [T13]: only rescale when the running max grew by > 8
    if (!__all(pm <= m_run + 8.f)) {
      float m_new = fmaxf(m_run, pm);
      float alpha = __expf(m_run - m_new);    // first tile: exp(-inf)=0
      float aj[4];
#pragma unroll
      for (int j = 0; j < 4; ++j) aj[j] = __shfl(alpha, lg * 4 + j);
#pragma unroll
      for (int nb = 0; nb < 4; ++nb)
#pragma unroll
        for (int j = 0; j < 4; ++j) accO[nb][j] *= aj[j];
      l_run *= alpha;
      m_run = m_new;
    }
    float p[16];
#pragma unroll
    for (int j = 0; j < 16; ++j) p[j] = __expf(s[j] - m_run);
    // tree sum
    float u8[8];
#pragma unroll
    for (int j = 0; j < 8; ++j) u8[j] = p[j] + p[j + 8];
    float u4a = u8[0] + u8[4], u4b = u8[1] + u8[5];
    float u4c = u8[2] + u8[6], u4d = u8[3] + u8[7];
    float psum = (u4a + u4b) + (u4c + u4d);
    psum += __shfl_xor(psum, 16);
    psum += __shfl_xor(psum, 32);
    l_run += psum;
    // P -> LDS (bf16), 4x 8B stores at P[q=l15][g*16+lg*4]
#pragma unroll
    for (int g = 0; g < 4; ++g) {
      ushort4v pk;
#pragma unroll
      for (int j = 0; j < 4; ++j) pk[j] = f2bf(p[g * 4 + j]);
      *(ushort4v*)&Pw[l15 * 72 + g * 16 + lg * 4] = pk;
    }
    // PV: A-frag from LDS P, B-frag from swizzled V tile  [T5 prio on MFMA cluster]
    __builtin_amdgcn_s_setprio(1);
#pragma unroll
    for (int ks = 0; ks < 2; ++ks) {
      short8 pa = *(const short8*)&Pw[l15 * 72 + ks * 32 + lg * 8];
#pragma unroll
      for (int nb = 0; nb < 4; ++nb) {
        short8 vb = *(const short8*)&Vb_[voff[ks][nb]];
        accO[nb] = __builtin_amdgcn_mfma_f32_16x16x32_bf16(pa, vb, accO[nb], 0, 0, 0);
      }
    }
    __builtin_amdgcn_s_setprio(0);
  };

  f32x4 cgA[4], cgB[4];
  stage(0);
  for (int t = 0; t < nt; t += 2) {
    // segment t (even): QK^T(t) || softmax+PV(t-1)
    __syncthreads();                          // stage(t) landed; buf rotation safe
    if (t + 1 < nt) stage(t + 1);
    QKT(t, cgA);
    if (t > 0) SOFTPV(t - 1, cgB);
    // segment t+1 (odd): QK^T(t+1) || softmax+PV(t)
    __syncthreads();
    if (t + 2 < nt) stage(t + 2);
    if (t + 1 < nt) QKT(t + 1, cgB);
    SOFTPV(t, cgA);
  }
  if ((nt & 1) == 0) SOFTPV(nt - 1, cgB);     // pending tile when nt even

  // epilogue: /l, write O[(b*T+t)][h*64+dh] bf16
  float lj[4];
#pragma unroll
  for (int j = 0; j < 4; ++j) lj[j] = 1.f / __shfl(l_run, lg * 4 + j);
  int b = hb >> 4, h = hb & 15;
#pragma unroll
  for (int nb = 0; nb < 4; ++nb)
#pragma unroll
    for (int j = 0; j < 4; ++j) {
      int t = q0 + lg * 4 + j;
      O[(size_t)(b * T_ + t) * D_ + h * DH_ + nb * 16 + l15] = f2bf(accO[nb][j] * lj[j]);
    }
}

extern "C" void kernel_launch(void* const* d_in, const int* in_sizes, int n_in,
                              void* d_out, int out_size, void* d_ws, size_t ws_size,
                              hipStream_t stream) {
  const float* x    = (const float*)d_in[0];
  const float* Wqkv = (const float*)d_in[1];
  const float* Wout = (const float*)d_in[2];
  const float* cosT = (const float*)d_in[3];
  const float* sinT = (const float*)d_in[4];
  // d_in[5] = mask (unused; causal handled analytically)
  float* out = (float*)d_out;
  char* ws = (char*)d_ws;
  // ws layout (bytes): 64 MB total
  unsigned short* Xb     = (unsigned short*)(ws);              //  8.0 MB  x bf16 [4096][1024]
  unsigned short* Wqkv_t = (unsigned short*)(ws + 8388608);    //  6.0 MB  Wqkv^T bf16 [3072][1024]
  unsigned short* Wout_t = (unsigned short*)(ws + 14680064);   //  2.0 MB  Wout^T bf16 [1024][1024]
  unsigned short* Ob     = (unsigned short*)(ws + 16777216);   //  8.0 MB  attn out bf16 [4096][1024]
  unsigned short* Qb     = (unsigned short*)(ws + 41943040);   //  8.0 MB  [BH][T][DH]
  unsigned short* Kb     = (unsigned short*)(ws + 50331648);   //  8.0 MB  [BH][T][DH]
  unsigned short* Vt     = (unsigned short*)(ws + 58720256);   //  8.0 MB  [BH][DH][T]

  k_cvt<<<4096, 256, 0, stream>>>(x, Xb);
  k_transpose<<<dim3(48, 16), 256, 0, stream>>>(Wqkv, Wqkv_t, 1024, 3072);
  k_transpose<<<dim3(16, 16), 256, 0, stream>>>(Wout, Wout_t, 1024, 1024);
  k_gemm_qkv_rope<<<dim3(24, 32), 256, 0, stream>>>(Xb, Wqkv_t, cosT, sinT, Qb, Kb, Vt);
  k_attn<<<1024, 256, 0, stream>>>(Qb, Kb, Vt, Ob);
  k_gemm_bt<float><<<dim3(8, 32), 256, 0, stream>>>(Ob, Wout_t, out, 4096, 1024, 1024);
}

// Round 21
// 131.221 us; speedup vs baseline: 1.0293x; 1.0293x over previous
//
#include <hip/hip_runtime.h>
#include <hip/hip_bf16.h>

// Fused attention fwd: x@Wqkv(+RoPE fused) -> causal flash attn (bf16 MFMA) -> @Wout
// B=2 T=2048 D=1024 H=16 DH=64
// R17/R19 best: 135.0us. This round: merge cvt+transposes into one k_prep launch.
#define B_ 2
#define T_ 2048
#define D_ 1024
#define H_ 16
#define DH_ 64
#define N3_ 3072
#define M_ 4096

typedef __attribute__((ext_vector_type(8))) short short8;      // 8 bf16 (4 VGPR) MFMA A/B frag
typedef __attribute__((ext_vector_type(4))) float f32x4;       // MFMA C/D frag
typedef __attribute__((ext_vector_type(4))) unsigned short ushort4v;

// native f32->bf16 (compiler emits hw cvt; RNE) [m240: scalar cast is the fast path]
__device__ __forceinline__ unsigned short f2bf(float f) {
  return __builtin_bit_cast(unsigned short, __hip_bfloat16(f));
}
__device__ __forceinline__ float bf2f(unsigned short u) {
  union { unsigned u; float f; } v; v.u = ((unsigned)u) << 16;
  return v.f;
}

// async global->LDS, 16B per lane; LDS dest is WAVE-UNIFORM base + lane*16 [m97/m104]
__device__ __forceinline__ void gload_lds16(const unsigned short* g, unsigned short* l) {
  __builtin_amdgcn_global_load_lds((const __attribute__((address_space(1))) void*)g,
                                   (__attribute__((address_space(3))) void*)l, 16, 0, 0);
}

// ---------- fused prep: f32->bf16 cvt (x) + both weight transposes ----------
// Three independent memory-bound jobs in ONE launch (were 3 serialized graph
// nodes): blocks [0,4096) cvt x->Xb; [4096,4864) Wqkv[1024][3072]->Wqkv_t;
// [4864,5120) Wout[1024][1024]->Wout_t.
__global__ __launch_bounds__(256)
void k_prep(const float* __restrict__ x, const float* __restrict__ Wqkv,
            const float* __restrict__ Wout, unsigned short* __restrict__ Xb,
            unsigned short* __restrict__ Wqkv_t, unsigned short* __restrict__ Wout_t) {
  __shared__ float tile[64][65];
  const int bid = blockIdx.x;
  if (bid < 4096) {                            // ---- cvt: 4 elems/thread
    int i = (bid * 256 + threadIdx.x) * 4;
    f32x4 v = *(const f32x4*)&x[i];
    ushort4v o;
    o[0] = f2bf(v[0]); o[1] = f2bf(v[1]); o[2] = f2bf(v[2]); o[3] = f2bf(v[3]);
    *(ushort4v*)&Xb[i] = o;
    return;
  }
  const float* in;
  unsigned short* out;
  int R, C, bx, by;
  if (bid < 4096 + 768) {                      // ---- Wqkv^T: 48x16 tiles
    int t = bid - 4096; in = Wqkv; out = Wqkv_t; R = 1024; C = 3072;
    bx = t % 48; by = t / 48;
  } else {                                     // ---- Wout^T: 16x16 tiles
    int t = bid - 4864; in = Wout; out = Wout_t; R = 1024; C = 1024;
    bx = t & 15; by = t >> 4;
  }
  int c0 = bx * 64, r0 = by * 64;
  int tx = threadIdx.x & 63, ty = threadIdx.x >> 6;
#pragma unroll
  for (int i = 0; i < 64; i += 4)
    tile[ty + i][tx] = in[(size_t)(r0 + ty + i) * C + c0 + tx];
  __syncthreads();
#pragma unroll
  for (int i = 0; i < 64; i += 4)
    out[(size_t)(c0 + ty + i) * R + r0 + tx] = f2bf(tile[tx][ty + i]);
}

// ---------- GEMM core (2-phase dbuf, BK=32, both-sides swizzle) [R17: -14.5us] ----------
#define GEMM_DBUF_LOOP(A_, Bt_, Kx_)                                               \
  const int l4 = lane >> 2, c4 = lane & 3;                                         \
  const int srcswz = ((c4 ^ (l4 & 3) ^ ((l4 >> 2) & 3)) << 3);                     \
  const int fswz = (((l15 & 3) ^ ((l15 >> 2) & 3)) << 3);                          \
  auto stage = [&](int buf, int k0) {                                              \
    _Pragma("unroll")                                                              \
    for (int i = 0; i < 2; ++i)                                                    \
      gload_lds16(&A_[(size_t)(m0 + wid * 32 + i * 16 + l4) * Kx_ + k0 + srcswz],  \
                  &As[buf * 4096 + (wid * 32 + i * 16) * 32]);                     \
    _Pragma("unroll")                                                              \
    for (int i = 0; i < 2; ++i)                                                    \
      gload_lds16(&Bt_[(size_t)(n0 + wid * 32 + i * 16 + l4) * Kx_ + k0 + srcswz], \
                  &Bs[buf * 4096 + (wid * 32 + i * 16) * 32]);                     \
  };                                                                               \
  const int KI = (Kx_) >> 5;                                                       \
  stage(0, 0);                                                                     \
  for (int it = 0; it < KI; ++it) {                                                \
    __syncthreads();                                                               \
    if (it + 1 < KI) stage((it + 1) & 1, (it + 1) << 5);                           \
    const unsigned short* As_ = &As[(it & 1) * 4096];                              \
    const unsigned short* Bs_ = &Bs[(it & 1) * 4096];                              \
    short8 af[4], bfr[4];                                                          \
    _Pragma("unroll")                                                              \
    for (int mi = 0; mi < 4; ++mi)                                                 \
      af[mi] = *(const short8*)&As_[(wr * 64 + mi * 16 + l15) * 32 +               \
                                    ((lg << 3) ^ fswz)];                           \
    _Pragma("unroll")                                                              \
    for (int ni = 0; ni < 4; ++ni)                                                 \
      bfr[ni] = *(const short8*)&Bs_[(wc * 64 + ni * 16 + l15) * 32 +              \
                                     ((lg << 3) ^ fswz)];                          \
    _Pragma("unroll")                                                              \
    for (int mi = 0; mi < 4; ++mi)                                                 \
      _Pragma("unroll")                                                            \
      for (int ni = 0; ni < 4; ++ni)                                               \
        acc[mi][ni] = __builtin_amdgcn_mfma_f32_16x16x32_bf16(af[mi], bfr[ni],     \
                                                              acc[mi][ni], 0, 0, 0); \
  }

// ---------- GEMM: C[M][N] = A[M][K] @ Bt[N][K]^T, bf16 in, OUT_T out ----------
template <typename OUT_T>
__global__ __launch_bounds__(256)
void k_gemm_bt(const unsigned short* __restrict__ A, const unsigned short* __restrict__ Bt,
               OUT_T* __restrict__ C, int Mx, int Nx, int Kx) {
  __shared__ __align__(16) unsigned short As[2 * 128 * 32];
  __shared__ __align__(16) unsigned short Bs[2 * 128 * 32];
  const int tid = threadIdx.x;
  const int lane = tid & 63;
  const int l15 = lane & 15, lg = lane >> 4;
  const int wid = tid >> 6;
  const int wr = wid >> 1, wc = wid & 1;
  const int m0 = blockIdx.y * 128, n0 = blockIdx.x * 128;

  const f32x4 zero4 = {0.f, 0.f, 0.f, 0.f};
  f32x4 acc[4][4];
#pragma unroll
  for (int mi = 0; mi < 4; ++mi)
#pragma unroll
    for (int ni = 0; ni < 4; ++ni) acc[mi][ni] = zero4;

  GEMM_DBUF_LOOP(A, Bt, Kx)

  // C/D layout: reg j -> row (lg*4+j), col l15  [verified m89/m91]
#pragma unroll
  for (int mi = 0; mi < 4; ++mi)
#pragma unroll
    for (int ni = 0; ni < 4; ++ni)
#pragma unroll
      for (int j = 0; j < 4; ++j) {
        int row = m0 + wr * 64 + mi * 16 + lg * 4 + j;
        int col = n0 + wc * 64 + ni * 16 + l15;
        float v = acc[mi][ni][j];
        if constexpr (sizeof(OUT_T) == 2) C[(size_t)row * Nx + col] = f2bf(v);
        else                              C[(size_t)row * Nx + col] = v;
      }
}

// ---------- fused QKV GEMM + RoPE + layout ----------
// C = Xb[4096][1024] @ Wqkv_t^T -> per-region epilogue:
//   cols [0,1024):   Q rope + 1/8 scale -> Q [BH][T][DH]
//   cols [1024,2048): K rope            -> K [BH][T][DH]
//   cols [2048,3072): V passthrough      -> Vt [BH][DH][T]
// RoPE pair (dh, dh+32) = (acc[mi][ni], acc[mi][ni+2]) for ni in {0,1} — in-register.
__global__ __launch_bounds__(256)
void k_gemm_qkv_rope(const unsigned short* __restrict__ A, const unsigned short* __restrict__ Bt,
                     const float* __restrict__ cosT, const float* __restrict__ sinT,
                     unsigned short* __restrict__ Q, unsigned short* __restrict__ K,
                     unsigned short* __restrict__ Vt) {
  __shared__ __align__(16) unsigned short As[2 * 128 * 32];
  __shared__ __align__(16) unsigned short Bs[2 * 128 * 32];
  const int tid = threadIdx.x;
  const int lane = tid & 63;
  const int l15 = lane & 15, lg = lane >> 4;
  const int wid = tid >> 6;
  const int wr = wid >> 1, wc = wid & 1;
  const int m0 = blockIdx.y * 128, n0 = blockIdx.x * 128;

  const f32x4 zero4 = {0.f, 0.f, 0.f, 0.f};
  f32x4 acc[4][4];
#pragma unroll
  for (int mi = 0; mi < 4; ++mi)
#pragma unroll
    for (int ni = 0; ni < 4; ++ni) acc[mi][ni] = zero4;

  GEMM_DBUF_LOOP(A, Bt, D_)

  const int region = n0 >> 10;                 // 0=Q 1=K 2=V (tile-aligned boundaries)
  const int h = (((n0 & 1023)) + wc * 64) >> 6;   // head of this wave's 64-col block
  if (region < 2) {
    unsigned short* out = (region == 0) ? Q : K;
    const float scale = (region == 0) ? 0.125f : 1.f;   // attn 1/sqrt(64) folded into Q
#pragma unroll
    for (int mi = 0; mi < 4; ++mi)
#pragma unroll
      for (int j = 0; j < 4; ++j) {
        int row = m0 + wr * 64 + mi * 16 + lg * 4 + j;
        int b = row >> 11, t = row & (T_ - 1);
        size_t obase = ((size_t)(b * H_ + h) * T_ + t) * DH_;
#pragma unroll
        for (int ni = 0; ni < 2; ++ni) {
          int dh = ni * 16 + l15;              // 0..31
          float cs = cosT[t * 32 + dh], sn = sinT[t * 32 + dh];
          float x1 = acc[mi][ni][j], x2 = acc[mi][ni + 2][j];
          out[obase + dh]      = f2bf((x1 * cs - x2 * sn) * scale);
          out[obase + dh + 32] = f2bf((x2 * cs + x1 * sn) * scale);
        }
      }
  } else {
#pragma unroll
    for (int mi = 0; mi < 4; ++mi) {
      int row0 = m0 + wr * 64 + mi * 16 + lg * 4;
      int b = row0 >> 11, t0 = row0 & (T_ - 1);
#pragma unroll
      for (int ni = 0; ni < 4; ++ni) {
        int col = (n0 - 2048) + wc * 64 + ni * 16 + l15;   // 0..1023
        int hv = col >> 6, dh = col & 63;
        ushort4v pk;
#pragma unroll
        for (int j = 0; j < 4; ++j) pk[j] = f2bf(acc[mi][ni][j]);
        *(ushort4v*)&Vt[((size_t)(b * H_ + hv) * DH_ + dh) * T_ + t0] = pk;
      }
    }
  }
}

// ---------- causal flash attention (block-cooperative, deferred-softmax pipeline) ----------
// [R17/R19 benched: ~59.5us] 4 waves x 16 q-rows, 1024 blocks. KV 64-key tiles:
// K 2-deep, V 3-deep LDS via gload_lds (both-sides swizzle). T15 att[2] pipeline
// (QK^T(t) || softmax+PV(t-1)). P via LDS stride-72. __expf softmax, defer-max
// THR=8, XCD-chunked swizzle. T5 setprio (R20: neutral, kept). Falsified:
// 32-row waves (R7), de-staging (R11), shuffle-P (R12), exp2f (R13),
// P-swizzle (R14), 8-wave (R18).
__global__ __launch_bounds__(256)
void k_attn(const unsigned short* __restrict__ Q, const unsigned short* __restrict__ K,
            const unsigned short* __restrict__ Vt, unsigned short* __restrict__ O) {
  __shared__ __align__(16) unsigned short Ks[2 * 64 * 64];   // [buf][r][chunk^(r&7)] 8KB/buf
  __shared__ __align__(16) unsigned short Vs[3 * 64 * 64];   // 3-deep, rows = dh
  __shared__ __align__(16) unsigned short Pl[4][16][72];     // per-wave P tile (64 + pad 8)
  const int tid = threadIdx.x;
  const int wid = tid >> 6, lane = tid & 63;
  const int l15 = lane & 15, lg = lane >> 4;
  const int l8 = lane >> 3, c8 = lane & 7;
  const int srcoff = (c8 ^ l8) << 3;          // swizzled source chunk (ushort units)
  // XCD-chunked bijective swizzle (nwg=1024): 128 blocks/XCD = 4 heads = 2MB K/V in L2.
  const int wg = (blockIdx.x & 7) * 128 + (blockIdx.x >> 3);
  const int qb = 31 - (wg & 31);              // reversed: longest jobs first
  const int hb = wg >> 5;                     // b*H + h
  const int qblk = qb * 64;
  const int q0 = qblk + wid * 16;
  const size_t hbase = (size_t)hb * T_ * DH_;
  const unsigned short* Qh = Q + hbase;
  const unsigned short* Kh = K + hbase;
  const unsigned short* Vh = Vt + hbase;      // [DH][T]
  unsigned short* Pw = &Pl[wid][0][0];

  // Q^T B-frags, hoisted (b[i] = Q[q0+l15][kk*32+lg*8+i])
  short8 bq0 = *(const short8*)&Qh[(q0 + l15) * DH_ + lg * 8];
  short8 bq1 = *(const short8*)&Qh[(q0 + l15) * DH_ + 32 + lg * 8];

  // hoisted swizzled LDS read offsets (kt-invariant; unrolled-const indexed)
  int koffA[4], koffB[4], voff[2][4];
#pragma unroll
  for (int g = 0; g < 4; ++g) {
    int r = g * 16 + l15;
    koffA[g] = r * 64 + (((lg)     ^ (r & 7)) << 3);
    koffB[g] = r * 64 + (((4 + lg) ^ (r & 7)) << 3);
  }
#pragma unroll
  for (int ks = 0; ks < 2; ++ks)
#pragma unroll
    for (int nb = 0; nb < 4; ++nb) {
      int r = nb * 16 + l15;
      voff[ks][nb] = r * 64 + (((ks * 4 + lg) ^ (r & 7)) << 3);
    }

  const f32x4 zero4 = {0.f, 0.f, 0.f, 0.f};
  f32x4 accO[4];
#pragma unroll
  for (int nb = 0; nb < 4; ++nb) accO[nb] = zero4;
  float m_run = -INFINITY, l_run = 0.f;
  const int qg = q0 + l15;
  const int nt = qb + 1;                      // block's 64-key tile count

  // stage K into Ks[t&1], V into Vs[t%3]: LDS[r][c] = X[r][c^(r&7)]
  auto stage = [&](int t) {
    const int kt = t << 6;
    if (wid < 2) {
      unsigned short* kb = &Ks[(t & 1) * 4096];
      const unsigned short* Kt = Kh + (size_t)kt * DH_;
#pragma unroll
      for (int i = 0; i < 4; ++i)
        gload_lds16(&Kt[(wid * 32 + i * 8 + l8) * DH_ + srcoff],
                    &kb[(wid * 4 + i) * 512]);
    } else {
      unsigned short* vb = &Vs[(t % 3) * 4096];
      const unsigned short* Vg = Vh + kt;
#pragma unroll
      for (int i = 0; i < 4; ++i)
        gload_lds16(&Vg[((wid - 2) * 32 + i * 8 + l8) * T_ + srcoff],
                    &vb[((wid - 2) * 4 + i) * 512]);
    }
  };

  // QK^T for tile t from Ks[t&1] into cg[4]  [T5: prio boost over peers' VALU]
  auto QKT = [&](int t, f32x4* cg) {
    const unsigned short* Kb_ = &Ks[(t & 1) * 4096];
    __builtin_amdgcn_s_setprio(1);
#pragma unroll
    for (int g = 0; g < 4; ++g) {
      short8 a0 = *(const short8*)&Kb_[koffA[g]];
      short8 a1 = *(const short8*)&Kb_[koffB[g]];
      cg[g] = __builtin_amdgcn_mfma_f32_16x16x32_bf16(a0, bq0, zero4, 0, 0, 0);
      cg[g] = __builtin_amdgcn_mfma_f32_16x16x32_bf16(a1, bq1, cg[g], 0, 0, 0);
    }
    __builtin_amdgcn_s_setprio(0);
  };

  // mask + online softmax + P write + PV for tile t (V from Vs[t%3])
  auto SOFTPV = [&](int t, f32x4* cg) {
    const int kt = t << 6;
    const unsigned short* Vb_ = &Vs[(t % 3) * 4096];
    float s[16];
#pragma unroll
    for (int g = 0; g < 4; ++g)
#pragma unroll
      for (int j = 0; j < 4; ++j) s[g * 4 + j] = cg[g][j];
    if (kt + 63 > q0) {                       // boundary tile: causal mask
#pragma unroll
      for (int g = 0; g < 4; ++g) {
        int kb0 = kt + g * 16 + lg * 4;
#pragma unroll
        for (int j = 0; j < 4; ++j)
          if (kb0 + j > qg) s[g * 4 + j] = -INFINITY;
      }
    }
    // tree max (depth 4)
    float t8[8];
#pragma unroll
    for (int j = 0; j < 8; ++j) t8[j] = fmaxf(s[j], s[j + 8]);
    float t4a = fmaxf(t8[0], t8[4]), t4b = fmaxf(t8[1], t8[5]);
    float t4c = fmaxf(t8[2], t8[6]), t4d = fmaxf(t8[3], t8[7]);
    float pm = fmaxf(fmaxf(t4a, t4b), fmaxf(t4c, t4d));
    pm = fmaxf(pm, __shfl_xor(pm, 16));
    pm = fmaxf(pm, __shfl_xor(pm, 32));
    // defer-max [T13]: only rescale when the running max grew by > 8
    if (!__all(pm <= m_run + 8.f)) {
      float m_new = fmaxf(m_run, pm);
      float alpha = __expf(m_run - m_new);    // first tile: exp(-inf)=0
      float aj[4];
#pragma unroll
      for (int j = 0; j < 4; ++j) aj[j] = __shfl(alpha, lg * 4 + j);
#pragma unroll
      for (int nb = 0; nb < 4; ++nb)
#pragma unroll
        for (int j = 0; j < 4; ++j) accO[nb][j] *= aj[j];
      l_run *= alpha;
      m_run = m_new;
    }
    float p[16];
#pragma unroll
    for (int j = 0; j < 16; ++j) p[j] = __expf(s[j] - m_run);
    // tree sum
    float u8[8];
#pragma unroll
    for (int j = 0; j < 8; ++j) u8[j] = p[j] + p[j + 8];
    float u4a = u8[0] + u8[4], u4b = u8[1] + u8[5];
    float u4c = u8[2] + u8[6], u4d = u8[3] + u8[7];
    float psum = (u4a + u4b) + (u4c + u4d);
    psum += __shfl_xor(psum, 16);
    psum += __shfl_xor(psum, 32);
    l_run += psum;
    // P -> LDS (bf16), 4x 8B stores at P[q=l15][g*16+lg*4]
#pragma unroll
    for (int g = 0; g < 4; ++g) {
      ushort4v pk;
#pragma unroll
      for (int j = 0; j < 4; ++j) pk[j] = f2bf(p[g * 4 + j]);
      *(ushort4v*)&Pw[l15 * 72 + g * 16 + lg * 4] = pk;
    }
    // PV: A-frag from LDS P, B-frag from swizzled V tile  [T5 prio on MFMA cluster]
    __builtin_amdgcn_s_setprio(1);
#pragma unroll
    for (int ks = 0; ks < 2; ++ks) {
      short8 pa = *(const short8*)&Pw[l15 * 72 + ks * 32 + lg * 8];
#pragma unroll
      for (int nb = 0; nb < 4; ++nb) {
        short8 vb = *(const short8*)&Vb_[voff[ks][nb]];
        accO[nb] = __builtin_amdgcn_mfma_f32_16x16x32_bf16(pa, vb, accO[nb], 0, 0, 0);
      }
    }
    __builtin_amdgcn_s_setprio(0);
  };

  f32x4 cgA[4], cgB[4];
  stage(0);
  for (int t = 0; t < nt; t += 2) {
    // segment t (even): QK^T(t) || softmax+PV(t-1)
    __syncthreads();                          // stage(t) landed; buf rotation safe
    if (t + 1 < nt) stage(t + 1);
    QKT(t, cgA);
    if (t > 0) SOFTPV(t - 1, cgB);
    // segment t+1 (odd): QK^T(t+1) || softmax+PV(t)
    __syncthreads();
    if (t + 2 < nt) stage(t + 2);
    if (t + 1 < nt) QKT(t + 1, cgB);
    SOFTPV(t, cgA);
  }
  if ((nt & 1) == 0) SOFTPV(nt - 1, cgB);     // pending tile when nt even

  // epilogue: /l, write O[(b*T+t)][h*64+dh] bf16
  float lj[4];
#pragma unroll
  for (int j = 0; j < 4; ++j) lj[j] = 1.f / __shfl(l_run, lg * 4 + j);
  int b = hb >> 4, h = hb & 15;
#pragma unroll
  for (int nb = 0; nb < 4; ++nb)
#pragma unroll
    for (int j = 0; j < 4; ++j) {
      int t = q0 + lg * 4 + j;
      O[(size_t)(b * T_ + t) * D_ + h * DH_ + nb * 16 + l15] = f2bf(accO[nb][j] * lj[j]);
    }
}

extern "C" void kernel_launch(void* const* d_in, const int* in_sizes, int n_in,
                              void* d_out, int out_size, void* d_ws, size_t ws_size,
                              hipStream_t stream) {
  const float* x    = (const float*)d_in[0];
  const float* Wqkv = (const float*)d_in[1];
  const float* Wout = (const float*)d_in[2];
  const float* cosT = (const float*)d_in[3];
  const float* sinT = (const float*)d_in[4];
  // d_in[5] = mask (unused; causal handled analytically)
  float* out = (float*)d_out;
  char* ws = (char*)d_ws;
  // ws layout (bytes): 64 MB total
  unsigned short* Xb     = (unsigned short*)(ws);              //  8.0 MB  x bf16 [4096][1024]
  unsigned short* Wqkv_t = (unsigned short*)(ws + 8388608);    //  6.0 MB  Wqkv^T bf16 [3072][1024]
  unsigned short* Wout_t = (unsigned short*)(ws + 14680064);   //  2.0 MB  Wout^T bf16 [1024][1024]
  unsigned short* Ob     = (unsigned short*)(ws + 16777216);   //  8.0 MB  attn out bf16 [4096][1024]
  unsigned short* Qb     = (unsigned short*)(ws + 41943040);   //  8.0 MB  [BH][T][DH]
  unsigned short* Kb     = (unsigned short*)(ws + 50331648);   //  8.0 MB  [BH][T][DH]
  unsigned short* Vt     = (unsigned short*)(ws + 58720256);   //  8.0 MB  [BH][DH][T]

  k_prep<<<5120, 256, 0, stream>>>(x, Wqkv, Wout, Xb, Wqkv_t, Wout_t);
  k_gemm_qkv_rope<<<dim3(24, 32), 256, 0, stream>>>(Xb, Wqkv_t, cosT, sinT, Qb, Kb, Vt);
  k_attn<<<1024, 256, 0, stream>>>(Qb, Kb, Vt, Ob);
  k_gemm_bt<float><<<dim3(8, 32), 256, 0, stream>>>(Ob, Wout_t, out, 4096, 1024, 1024);
}

// Round 22
// 130.436 us; speedup vs baseline: 1.0355x; 1.0060x over previous
//
#include <hip/hip_runtime.h>
#include <hip/hip_bf16.h>

// Fused attention fwd: x@Wqkv(+RoPE fused) -> causal flash attn (bf16 MFMA) -> @Wout
// B=2 T=2048 D=1024 H=16 DH=64
// R21 best: 131.2us. This round: QKV GEMM -> 256^2 / 8-wave / BK=64 geometry.
#define B_ 2
#define T_ 2048
#define D_ 1024
#define H_ 16
#define DH_ 64
#define N3_ 3072
#define M_ 4096

typedef __attribute__((ext_vector_type(8))) short short8;      // 8 bf16 (4 VGPR) MFMA A/B frag
typedef __attribute__((ext_vector_type(4))) float f32x4;       // MFMA C/D frag
typedef __attribute__((ext_vector_type(4))) unsigned short ushort4v;

// native f32->bf16 (compiler emits hw cvt; RNE) [m240: scalar cast is the fast path]
__device__ __forceinline__ unsigned short f2bf(float f) {
  return __builtin_bit_cast(unsigned short, __hip_bfloat16(f));
}
__device__ __forceinline__ float bf2f(unsigned short u) {
  union { unsigned u; float f; } v; v.u = ((unsigned)u) << 16;
  return v.f;
}

// async global->LDS, 16B per lane; LDS dest is WAVE-UNIFORM base + lane*16 [m97/m104]
__device__ __forceinline__ void gload_lds16(const unsigned short* g, unsigned short* l) {
  __builtin_amdgcn_global_load_lds((const __attribute__((address_space(1))) void*)g,
                                   (__attribute__((address_space(3))) void*)l, 16, 0, 0);
}

// ---------- fused prep: f32->bf16 cvt (x) + both weight transposes [R21: -3.8us] ----------
__global__ __launch_bounds__(256)
void k_prep(const float* __restrict__ x, const float* __restrict__ Wqkv,
            const float* __restrict__ Wout, unsigned short* __restrict__ Xb,
            unsigned short* __restrict__ Wqkv_t, unsigned short* __restrict__ Wout_t) {
  __shared__ float tile[64][65];
  const int bid = blockIdx.x;
  if (bid < 4096) {                            // ---- cvt: 4 elems/thread
    int i = (bid * 256 + threadIdx.x) * 4;
    f32x4 v = *(const f32x4*)&x[i];
    ushort4v o;
    o[0] = f2bf(v[0]); o[1] = f2bf(v[1]); o[2] = f2bf(v[2]); o[3] = f2bf(v[3]);
    *(ushort4v*)&Xb[i] = o;
    return;
  }
  const float* in;
  unsigned short* out;
  int R, C, bx, by;
  if (bid < 4096 + 768) {                      // ---- Wqkv^T: 48x16 tiles
    int t = bid - 4096; in = Wqkv; out = Wqkv_t; R = 1024; C = 3072;
    bx = t % 48; by = t / 48;
  } else {                                     // ---- Wout^T: 16x16 tiles
    int t = bid - 4864; in = Wout; out = Wout_t; R = 1024; C = 1024;
    bx = t & 15; by = t >> 4;
  }
  int c0 = bx * 64, r0 = by * 64;
  int tx = threadIdx.x & 63, ty = threadIdx.x >> 6;
#pragma unroll
  for (int i = 0; i < 64; i += 4)
    tile[ty + i][tx] = in[(size_t)(r0 + ty + i) * C + c0 + tx];
  __syncthreads();
#pragma unroll
  for (int i = 0; i < 64; i += 4)
    out[(size_t)(c0 + ty + i) * R + r0 + tx] = f2bf(tile[tx][ty + i]);
}

// ---------- GEMM core (2-phase dbuf, BK=32, both-sides swizzle) [R17: -14.5us] ----------
#define GEMM_DBUF_LOOP(A_, Bt_, Kx_)                                               \
  const int l4 = lane >> 2, c4 = lane & 3;                                         \
  const int srcswz = ((c4 ^ (l4 & 3) ^ ((l4 >> 2) & 3)) << 3);                     \
  const int fswz = (((l15 & 3) ^ ((l15 >> 2) & 3)) << 3);                          \
  auto stage = [&](int buf, int k0) {                                              \
    _Pragma("unroll")                                                              \
    for (int i = 0; i < 2; ++i)                                                    \
      gload_lds16(&A_[(size_t)(m0 + wid * 32 + i * 16 + l4) * Kx_ + k0 + srcswz],  \
                  &As[buf * 4096 + (wid * 32 + i * 16) * 32]);                     \
    _Pragma("unroll")                                                              \
    for (int i = 0; i < 2; ++i)                                                    \
      gload_lds16(&Bt_[(size_t)(n0 + wid * 32 + i * 16 + l4) * Kx_ + k0 + srcswz], \
                  &Bs[buf * 4096 + (wid * 32 + i * 16) * 32]);                     \
  };                                                                               \
  const int KI = (Kx_) >> 5;                                                       \
  stage(0, 0);                                                                     \
  for (int it = 0; it < KI; ++it) {                                                \
    __syncthreads();                                                               \
    if (it + 1 < KI) stage((it + 1) & 1, (it + 1) << 5);                           \
    const unsigned short* As_ = &As[(it & 1) * 4096];                              \
    const unsigned short* Bs_ = &Bs[(it & 1) * 4096];                              \
    short8 af[4], bfr[4];                                                          \
    _Pragma("unroll")                                                              \
    for (int mi = 0; mi < 4; ++mi)                                                 \
      af[mi] = *(const short8*)&As_[(wr * 64 + mi * 16 + l15) * 32 +               \
                                    ((lg << 3) ^ fswz)];                           \
    _Pragma("unroll")                                                              \
    for (int ni = 0; ni < 4; ++ni)                                                 \
      bfr[ni] = *(const short8*)&Bs_[(wc * 64 + ni * 16 + l15) * 32 +              \
                                     ((lg << 3) ^ fswz)];                          \
    _Pragma("unroll")                                                              \
    for (int mi = 0; mi < 4; ++mi)                                                 \
      _Pragma("unroll")                                                            \
      for (int ni = 0; ni < 4; ++ni)                                               \
        acc[mi][ni] = __builtin_amdgcn_mfma_f32_16x16x32_bf16(af[mi], bfr[ni],     \
                                                              acc[mi][ni], 0, 0, 0); \
  }

// ---------- GEMM: C[M][N] = A[M][K] @ Bt[N][K]^T, bf16 in, OUT_T out ----------
template <typename OUT_T>
__global__ __launch_bounds__(256)
void k_gemm_bt(const unsigned short* __restrict__ A, const unsigned short* __restrict__ Bt,
               OUT_T* __restrict__ C, int Mx, int Nx, int Kx) {
  __shared__ __align__(16) unsigned short As[2 * 128 * 32];
  __shared__ __align__(16) unsigned short Bs[2 * 128 * 32];
  const int tid = threadIdx.x;
  const int lane = tid & 63;
  const int l15 = lane & 15, lg = lane >> 4;
  const int wid = tid >> 6;
  const int wr = wid >> 1, wc = wid & 1;
  const int m0 = blockIdx.y * 128, n0 = blockIdx.x * 128;

  const f32x4 zero4 = {0.f, 0.f, 0.f, 0.f};
  f32x4 acc[4][4];
#pragma unroll
  for (int mi = 0; mi < 4; ++mi)
#pragma unroll
    for (int ni = 0; ni < 4; ++ni) acc[mi][ni] = zero4;

  GEMM_DBUF_LOOP(A, Bt, Kx)

  // C/D layout: reg j -> row (lg*4+j), col l15  [verified m89/m91]
#pragma unroll
  for (int mi = 0; mi < 4; ++mi)
#pragma unroll
    for (int ni = 0; ni < 4; ++ni)
#pragma unroll
      for (int j = 0; j < 4; ++j) {
        int row = m0 + wr * 64 + mi * 16 + lg * 4 + j;
        int col = n0 + wc * 64 + ni * 16 + l15;
        float v = acc[mi][ni][j];
        if constexpr (sizeof(OUT_T) == 2) C[(size_t)row * Nx + col] = f2bf(v);
        else                              C[(size_t)row * Nx + col] = v;
      }
}

// ---------- fused QKV GEMM + RoPE + layout (256^2 tile, 8 waves, BK=64) ----------
// C = Xb[4096][1024] @ Wqkv_t^T. Grid 12x16 (192 blocks, all co-resident,
// 1 block/CU @ 128KB LDS). Wave (wr=wid>>2, wc=wid&3) owns 128 rows x 64 cols:
// acc[8][4]. Staging: gload_lds w16, both-sides chunk^(r&7) swizzle (attn-verified
// algebra; read banks 2-way/free). One raw vmcnt(0)+s_barrier per K-tile (loads
// issued a full tile earlier -> drain is covered; half the barriers of BK=32).
// B-frags read once per kk, reused across both M-halves (24 ds_reads / 64 MFMA).
// Epilogue: region boundaries (1024,2048) are 256-aligned -> per-tile uniform.
__global__ __launch_bounds__(512, 2)
void k_gemm_qkv_rope(const unsigned short* __restrict__ A, const unsigned short* __restrict__ Bt,
                     const float* __restrict__ cosT, const float* __restrict__ sinT,
                     unsigned short* __restrict__ Q, unsigned short* __restrict__ K,
                     unsigned short* __restrict__ Vt) {
  __shared__ __align__(16) unsigned short As[2 * 256 * 64];   // 64KB
  __shared__ __align__(16) unsigned short Bs[2 * 256 * 64];   // 64KB
  const int Kx = D_;
  const int tid = threadIdx.x;
  const int lane = tid & 63;
  const int l15 = lane & 15, lg = lane >> 4;
  const int l8 = lane >> 3, c8 = lane & 7;
  const int srcoff = (c8 ^ l8) << 3;           // swizzled source chunk (ushort units)
  const int wid = tid >> 6;                    // 0..7
  const int wr = wid >> 2, wc = wid & 3;
  const int m0 = blockIdx.y * 256, n0 = blockIdx.x * 256;

  const f32x4 zero4 = {0.f, 0.f, 0.f, 0.f};
  f32x4 acc[8][4];
#pragma unroll
  for (int ar = 0; ar < 8; ++ar)
#pragma unroll
    for (int ni = 0; ni < 4; ++ni) acc[ar][ni] = zero4;

  // stage K-tile t into buf t&1: each wave stages 32 rows of A and of B
  // (4 calls x 8 rows each); LDS[r][c] = X[r][c^(r&7)].
  auto stage = [&](int t) {
    const int k0 = t << 6;
    unsigned short* abuf = &As[(t & 1) * 16384];
    unsigned short* bbuf = &Bs[(t & 1) * 16384];
#pragma unroll
    for (int i = 0; i < 4; ++i)
      gload_lds16(&A[(size_t)(m0 + wid * 32 + i * 8 + l8) * Kx + k0 + srcoff],
                  &abuf[(wid * 32 + i * 8) * 64]);
#pragma unroll
    for (int i = 0; i < 4; ++i)
      gload_lds16(&Bt[(size_t)(n0 + wid * 32 + i * 8 + l8) * Kx + k0 + srcoff],
                  &bbuf[(wid * 32 + i * 8) * 64]);
  };

  stage(0);
  asm volatile("s_waitcnt vmcnt(0)\ns_barrier" ::: "memory");
  for (int t = 0; t < 16; ++t) {
    if (t + 1 < 16) stage(t + 1);              // lands before next tile's barrier
    const unsigned short* As_ = &As[(t & 1) * 16384];
    const unsigned short* Bs_ = &Bs[(t & 1) * 16384];
#pragma unroll
    for (int kk = 0; kk < 2; ++kk) {
      short8 bf[4];
#pragma unroll
      for (int ni = 0; ni < 4; ++ni) {
        int r = wc * 64 + ni * 16 + l15;
        bf[ni] = *(const short8*)&Bs_[r * 64 + (((kk * 4 + lg) ^ (r & 7)) << 3)];
      }
#pragma unroll
      for (int mh = 0; mh < 2; ++mh) {
        short8 af[4];
#pragma unroll
        for (int mi = 0; mi < 4; ++mi) {
          int r = wr * 128 + mh * 64 + mi * 16 + l15;
          af[mi] = *(const short8*)&As_[r * 64 + (((kk * 4 + lg) ^ (r & 7)) << 3)];
        }
#pragma unroll
        for (int mi = 0; mi < 4; ++mi)
#pragma unroll
          for (int ni = 0; ni < 4; ++ni)
            acc[mh * 4 + mi][ni] = __builtin_amdgcn_mfma_f32_16x16x32_bf16(
                af[mi], bf[ni], acc[mh * 4 + mi][ni], 0, 0, 0);
      }
    }
    // all waves past this tile's reads; own stage loads drained -> barrier joins all
    asm volatile("s_waitcnt vmcnt(0)\ns_barrier" ::: "memory");
  }

  const int region = n0 >> 10;                 // 0=Q 1=K 2=V (256-aligned boundaries)
  const int h = ((n0 & 1023) + wc * 64) >> 6;  // head of this wave's 64-col block
  if (region < 2) {
    unsigned short* out = (region == 0) ? Q : K;
    const float scale = (region == 0) ? 0.125f : 1.f;   // attn 1/sqrt(64) folded into Q
#pragma unroll
    for (int ar = 0; ar < 8; ++ar)
#pragma unroll
      for (int j = 0; j < 4; ++j) {
        int row = m0 + wr * 128 + ar * 16 + lg * 4 + j;
        int b = row >> 11, tt = row & (T_ - 1);
        size_t obase = ((size_t)(b * H_ + h) * T_ + tt) * DH_;
#pragma unroll
        for (int ni = 0; ni < 2; ++ni) {
          int dh = ni * 16 + l15;              // 0..31
          float cs = cosT[tt * 32 + dh], sn = sinT[tt * 32 + dh];
          float x1 = acc[ar][ni][j], x2 = acc[ar][ni + 2][j];
          out[obase + dh]      = f2bf((x1 * cs - x2 * sn) * scale);
          out[obase + dh + 32] = f2bf((x2 * cs + x1 * sn) * scale);
        }
      }
  } else {
#pragma unroll
    for (int ar = 0; ar < 8; ++ar) {
      int row0 = m0 + wr * 128 + ar * 16 + lg * 4;
      int b = row0 >> 11, t0 = row0 & (T_ - 1);
#pragma unroll
      for (int ni = 0; ni < 4; ++ni) {
        int col = (n0 - 2048) + wc * 64 + ni * 16 + l15;   // 0..1023
        int hv = col >> 6, dh = col & 63;
        ushort4v pk;
#pragma unroll
        for (int j = 0; j < 4; ++j) pk[j] = f2bf(acc[ar][ni][j]);
        *(ushort4v*)&Vt[((size_t)(b * H_ + hv) * DH_ + dh) * T_ + t0] = pk;
      }
    }
  }
}

// ---------- causal flash attention (block-cooperative, deferred-softmax pipeline) ----------
// [R17/R19 benched: ~59.5us] 4 waves x 16 q-rows, 1024 blocks. KV 64-key tiles:
// K 2-deep, V 3-deep LDS via gload_lds (both-sides swizzle). T15 att[2] pipeline
// (QK^T(t) || softmax+PV(t-1)). P via LDS stride-72. __expf softmax, defer-max
// THR=8, XCD-chunked swizzle. T5 setprio (R20: neutral, kept). Falsified:
// 32-row waves (R7), de-staging (R11), shuffle-P (R12), exp2f (R13),
// P-swizzle (R14), 8-wave (R18).
__global__ __launch_bounds__(256)
void k_attn(const unsigned short* __restrict__ Q, const unsigned short* __restrict__ K,
            const unsigned short* __restrict__ Vt, unsigned short* __restrict__ O) {
  __shared__ __align__(16) unsigned short Ks[2 * 64 * 64];   // [buf][r][chunk^(r&7)] 8KB/buf
  __shared__ __align__(16) unsigned short Vs[3 * 64 * 64];   // 3-deep, rows = dh
  __shared__ __align__(16) unsigned short Pl[4][16][72];     // per-wave P tile (64 + pad 8)
  const int tid = threadIdx.x;
  const int wid = tid >> 6, lane = tid & 63;
  const int l15 = lane & 15, lg = lane >> 4;
  const int l8 = lane >> 3, c8 = lane & 7;
  const int srcoff = (c8 ^ l8) << 3;          // swizzled source chunk (ushort units)
  // XCD-chunked bijective swizzle (nwg=1024): 128 blocks/XCD = 4 heads = 2MB K/V in L2.
  const int wg = (blockIdx.x & 7) * 128 + (blockIdx.x >> 3);
  const int qb = 31 - (wg & 31);              // reversed: longest jobs first
  const int hb = wg >> 5;                     // b*H + h
  const int qblk = qb * 64;
  const int q0 = qblk + wid * 16;
  const size_t hbase = (size_t)hb * T_ * DH_;
  const unsigned short* Qh = Q + hbase;
  const unsigned short* Kh = K + hbase;
  const unsigned short* Vh = Vt + hbase;      // [DH][T]
  unsigned short* Pw = &Pl[wid][0][0];

  // Q^T B-frags, hoisted (b[i] = Q[q0+l15][kk*32+lg*8+i])
  short8 bq0 = *(const short8*)&Qh[(q0 + l15) * DH_ + lg * 8];
  short8 bq1 = *(const short8*)&Qh[(q0 + l15) * DH_ + 32 + lg * 8];

  // hoisted swizzled LDS read offsets (kt-invariant; unrolled-const indexed)
  int koffA[4], koffB[4], voff[2][4];
#pragma unroll
  for (int g = 0; g < 4; ++g) {
    int r = g * 16 + l15;
    koffA[g] = r * 64 + (((lg)     ^ (r & 7)) << 3);
    koffB[g] = r * 64 + (((4 + lg) ^ (r & 7)) << 3);
  }
#pragma unroll
  for (int ks = 0; ks < 2; ++ks)
#pragma unroll
    for (int nb = 0; nb < 4; ++nb) {
      int r = nb * 16 + l15;
      voff[ks][nb] = r * 64 + (((ks * 4 + lg) ^ (r & 7)) << 3);
    }

  const f32x4 zero4 = {0.f, 0.f, 0.f, 0.f};
  f32x4 accO[4];
#pragma unroll
  for (int nb = 0; nb < 4; ++nb) accO[nb] = zero4;
  float m_run = -INFINITY, l_run = 0.f;
  const int qg = q0 + l15;
  const int nt = qb + 1;                      // block's 64-key tile count

  // stage K into Ks[t&1], V into Vs[t%3]: LDS[r][c] = X[r][c^(r&7)]
  auto stage = [&](int t) {
    const int kt = t << 6;
    if (wid < 2) {
      unsigned short* kb = &Ks[(t & 1) * 4096];
      const unsigned short* Kt = Kh + (size_t)kt * DH_;
#pragma unroll
      for (int i = 0; i < 4; ++i)
        gload_lds16(&Kt[(wid * 32 + i * 8 + l8) * DH_ + srcoff],
                    &kb[(wid * 4 + i) * 512]);
    } else {
      unsigned short* vb = &Vs[(t % 3) * 4096];
      const unsigned short* Vg = Vh + kt;
#pragma unroll
      for (int i = 0; i < 4; ++i)
        gload_lds16(&Vg[((wid - 2) * 32 + i * 8 + l8) * T_ + srcoff],
                    &vb[((wid - 2) * 4 + i) * 512]);
    }
  };

  // QK^T for tile t from Ks[t&1] into cg[4]  [T5: prio boost over peers' VALU]
  auto QKT = [&](int t, f32x4* cg) {
    const unsigned short* Kb_ = &Ks[(t & 1) * 4096];
    __builtin_amdgcn_s_setprio(1);
#pragma unroll
    for (int g = 0; g < 4; ++g) {
      short8 a0 = *(const short8*)&Kb_[koffA[g]];
      short8 a1 = *(const short8*)&Kb_[koffB[g]];
      cg[g] = __builtin_amdgcn_mfma_f32_16x16x32_bf16(a0, bq0, zero4, 0, 0, 0);
      cg[g] = __builtin_amdgcn_mfma_f32_16x16x32_bf16(a1, bq1, cg[g], 0, 0, 0);
    }
    __builtin_amdgcn_s_setprio(0);
  };

  // mask + online softmax + P write + PV for tile t (V from Vs[t%3])
  auto SOFTPV = [&](int t, f32x4* cg) {
    const int kt = t << 6;
    const unsigned short* Vb_ = &Vs[(t % 3) * 4096];
    float s[16];
#pragma unroll
    for (int g = 0; g < 4; ++g)
#pragma unroll
      for (int j = 0; j < 4; ++j) s[g * 4 + j] = cg[g][j];
    if (kt + 63 > q0) {                       // boundary tile: causal mask
#pragma unroll
      for (int g = 0; g < 4; ++g) {
        int kb0 = kt + g * 16 + lg * 4;
#pragma unroll
        for (int j = 0; j < 4; ++j)
          if (kb0 + j > qg) s[g * 4 + j] = -INFINITY;
      }
    }
    // tree max (depth 4)
    float t8[8];
#pragma unroll
    for (int j = 0; j < 8; ++j) t8[j] = fmaxf(s[j], s[j + 8]);
    float t4a = fmaxf(t8[0], t8[4]), t4b = fmaxf(t8[1], t8[5]);
    float t4c = fmaxf(t8[2], t8[6]), t4d = fmaxf(t8[3], t8[7]);
    float pm = fmaxf(fmaxf(t4a, t4b), fmaxf(t4c, t4d));
    pm = fmaxf(pm, __shfl_xor(pm, 16));
    pm = fmaxf(pm, __shfl_xor(pm, 32));
    // defer-max [T13]: only rescale when the running max grew by > 8
    if (!__all(pm <= m_run + 8.f)) {
      float m_new = fmaxf(m_run, pm);
      float alpha = __expf(m_run - m_new);    // first tile: exp(-inf)=0
      float aj[4];
#pragma unroll
      for (int j = 0; j < 4; ++j) aj[j] = __shfl(alpha, lg * 4 + j);
#pragma unroll
      for (int nb = 0; nb < 4; ++nb)
#pragma unroll
        for (int j = 0; j < 4; ++j) accO[nb][j] *= aj[j];
      l_run *= alpha;
      m_run = m_new;
    }
    float p[16];
#pragma unroll
    for (int j = 0; j < 16; ++j) p[j] = __expf(s[j] - m_run);
    // tree sum
    float u8[8];
#pragma unroll
    for (int j = 0; j < 8; ++j) u8[j] = p[j] + p[j + 8];
    float u4a = u8[0] + u8[4], u4b = u8[1] + u8[5];
    float u4c = u8[2] + u8[6], u4d = u8[3] + u8[7];
    float psum = (u4a + u4b) + (u4c + u4d);
    psum += __shfl_xor(psum, 16);
    psum += __shfl_xor(psum, 32);
    l_run += psum;
    // P -> LDS (bf16), 4x 8B stores at P[q=l15][g*16+lg*4]
#pragma unroll
    for (int g = 0; g < 4; ++g) {
      ushort4v pk;
#pragma unroll
      for (int j = 0; j < 4; ++j) pk[j] = f2bf(p[g * 4 + j]);
      *(ushort4v*)&Pw[l15 * 72 + g * 16 + lg * 4] = pk;
    }
    // PV: A-frag from LDS P, B-frag from swizzled V tile  [T5 prio on MFMA cluster]
    __builtin_amdgcn_s_setprio(1);
#pragma unroll
    for (int ks = 0; ks < 2; ++ks) {
      short8 pa = *(const short8*)&Pw[l15 * 72 + ks * 32 + lg * 8];
#pragma unroll
      for (int nb = 0; nb < 4; ++nb) {
        short8 vb = *(const short8*)&Vb_[voff[ks][nb]];
        accO[nb] = __builtin_amdgcn_mfma_f32_16x16x32_bf16(pa, vb, accO[nb], 0, 0, 0);
      }
    }
    __builtin_amdgcn_s_setprio(0);
  };

  f32x4 cgA[4], cgB[4];
  stage(0);
  for (int t = 0; t < nt; t += 2) {
    // segment t (even): QK^T(t) || softmax+PV(t-1)
    __syncthreads();                          // stage(t) landed; buf rotation safe
    if (t + 1 < nt) stage(t + 1);
    QKT(t, cgA);
    if (t > 0) SOFTPV(t - 1, cgB);
    // segment t+1 (odd): QK^T(t+1) || softmax+PV(t)
    __syncthreads();
    if (t + 2 < nt) stage(t + 2);
    if (t + 1 < nt) QKT(t + 1, cgB);
    SOFTPV(t, cgA);
  }
  if ((nt & 1) == 0) SOFTPV(nt - 1, cgB);     // pending tile when nt even

  // epilogue: /l, write O[(b*T+t)][h*64+dh] bf16
  float lj[4];
#pragma unroll
  for (int j = 0; j < 4; ++j) lj[j] = 1.f / __shfl(l_run, lg * 4 + j);
  int b = hb >> 4, h = hb & 15;
#pragma unroll
  for (int nb = 0; nb < 4; ++nb)
#pragma unroll
    for (int j = 0; j < 4; ++j) {
      int t = q0 + lg * 4 + j;
      O[(size_t)(b * T_ + t) * D_ + h * DH_ + nb * 16 + l15] = f2bf(accO[nb][j] * lj[j]);
    }
}

extern "C" void kernel_launch(void* const* d_in, const int* in_sizes, int n_in,
                              void* d_out, int out_size, void* d_ws, size_t ws_size,
                              hipStream_t stream) {
  const float* x    = (const float*)d_in[0];
  const float* Wqkv = (const float*)d_in[1];
  const float* Wout = (const float*)d_in[2];
  const float* cosT = (const float*)d_in[3];
  const float* sinT = (const float*)d_in[4];
  // d_in[5] = mask (unused; causal handled analytically)
  float* out = (float*)d_out;
  char* ws = (char*)d_ws;
  // ws layout (bytes): 64 MB total
  unsigned short* Xb     = (unsigned short*)(ws);              //  8.0 MB  x bf16 [4096][1024]
  unsigned short* Wqkv_t = (unsigned short*)(ws + 8388608);    //  6.0 MB  Wqkv^T bf16 [3072][1024]
  unsigned short* Wout_t = (unsigned short*)(ws + 14680064);   //  2.0 MB  Wout^T bf16 [1024][1024]
  unsigned short* Ob     = (unsigned short*)(ws + 16777216);   //  8.0 MB  attn out bf16 [4096][1024]
  unsigned short* Qb     = (unsigned short*)(ws + 41943040);   //  8.0 MB  [BH][T][DH]
  unsigned short* Kb     = (unsigned short*)(ws + 50331648);   //  8.0 MB  [BH][T][DH]
  unsigned short* Vt     = (unsigned short*)(ws + 58720256);   //  8.0 MB  [BH][DH][T]

  k_prep<<<5120, 256, 0, stream>>>(x, Wqkv, Wout, Xb, Wqkv_t, Wout_t);
  k_gemm_qkv_rope<<<dim3(12, 16), 512, 0, stream>>>(Xb, Wqkv_t, cosT, sinT, Qb, Kb, Vt);
  k_attn<<<1024, 256, 0, stream>>>(Qb, Kb, Vt, Ob);
  k_gemm_bt<float><<<dim3(8, 32), 256, 0, stream>>>(Ob, Wout_t, out, 4096, 1024, 1024);
}